// Round 11
// baseline (208.682 us; speedup 1.0000x reference)
//
#include <hip/hip_runtime.h>
#include <hip/hip_bf16.h>
#include <hip/hip_fp16.h>
#include <math.h>

// Problem constants
#define BB   8
#define CIN  256
#define HH   64
#define WW   64
#define OMC  27          // 3*K offset/mask channels
#define HW   (HH*WW)
#define KTOT (CIN*9)     // 2304 GEMM K
#define NPIX 32          // pixels per block (N tile)
#define SPITCH 296       // LDS sample row pitch in halves (288 + 8 pad)
#define XP1    40        // pass-1 bf16 tile ch pitch (halves)
#define TPW    17        // pass-2 tile words per rc entry (32ch bf16 + 1 pad word)

typedef short bf16x8 __attribute__((ext_vector_type(8)));
typedef float f32x4  __attribute__((ext_vector_type(4)));

__device__ __forceinline__ unsigned short f2bf(float f) {
    union { float f; unsigned int u; } v; v.f = f;
    unsigned int r = v.u + 0x7FFFu + ((v.u >> 16) & 1u);   // RNE
    return (unsigned short)(r >> 16);
}
__device__ __forceinline__ float bflo(unsigned int a) {
    union { unsigned int u; float f; } c; c.u = a << 16; return c.f;
}
__device__ __forceinline__ float bfhi(unsigned int a) {
    union { unsigned int u; float f; } c; c.u = a & 0xFFFF0000u; return c.f;
}

// ---------------------------------------------------------------------------
// Kernel 0a: w_dc (fp32 [o][c*9+tap]) -> bf16 wA, TAP-MAJOR chunk-local k:
//   k' = (c>>5)*288 + tap*32 + (c&31);  wA[k'>>3][o][k'&7]
// ---------------------------------------------------------------------------
__global__ __launch_bounds__(256) void wprep_kernel(
    const float* __restrict__ w_dc, unsigned short* __restrict__ wA)
{
    int e = blockIdx.x * 256 + threadIdx.x;          // 256*2304 elements
    int o = e / KTOT;
    int k = e - o * KTOT;
    int c   = k / 9;
    int tap = k - c * 9;
    int kp  = (c >> 5) * 288 + tap * 32 + (c & 31);
    wA[((size_t)(kp >> 3) * 256 + o) * 8 + (kp & 7)] = f2bf(w_dc[e]);
}

// ---------------------------------------------------------------------------
// Kernel 0b: w_om (fp32 [27][256][9]) -> bf16 padded/swizzled:
// wOmA[(((tap*8+cc)*4 + cb)*32 + o)*8 + j], channel c = cc*32+cb*8+j, o<32pad.
// ---------------------------------------------------------------------------
__global__ __launch_bounds__(256) void womprep_kernel(
    const float* __restrict__ w_om, unsigned short* __restrict__ wOmA)
{
    int e = blockIdx.x * 256 + threadIdx.x;          // 73728
    int j  = e & 7;
    int t1 = e >> 3;
    int o  = t1 & 31;
    int t2 = t1 >> 5;
    int cb = t2 & 3;
    int t3 = t2 >> 2;
    int cc = t3 & 7;
    int tap = t3 >> 3;
    int c = cc * 32 + cb * 8 + j;
    float v = (o < OMC) ? w_om[(size_t)o * KTOT + c * 9 + tap] : 0.f;
    wOmA[e] = f2bf(v);
}

// ---------------------------------------------------------------------------
// Fused kernel, 512 threads (8 waves). M=256, N=32 pixels, K=2304.
// Pass 1: om-conv from bf16 [rc][ch] tile (dbuf, b128 frags).
// Pass 2: bilinear gather from CHANNEL-INTERLEAVED bf16 tile
//         ([rc][32ch], 17-word pitch, reg-staged T14-style), 4 b32/tap/2ch,
//         fp16-packed folded weights, bf16 MFMA GEMM.
// The sR overhang words [3400,4112) are read (weight-0 corners) but never
// staged -> zeroed ONCE in the prologue (leftover-LDS NaN guard, R10 bug).
// ---------------------------------------------------------------------------
__global__ __launch_bounds__(512, 8) void deform_mfma_kernel(
    const float* __restrict__ x, const unsigned short* __restrict__ wOmA,
    const float* __restrict__ b_om,
    const unsigned short* __restrict__ wA, const float* __restrict__ b_dc,
    float* __restrict__ out)
{
    const int bid  = blockIdx.x;         // b*128 + h*2 + wt
    const int b    = bid >> 7;
    const int h    = (bid >> 1) & 63;
    const int w0   = (bid & 1) * NPIX;
    const int t    = threadIdx.x;
    const int wv   = t >> 6;             // wave 0..7
    const int lane = t & 63;
    const int lq   = lane >> 4;          // k-quarter
    const int lm   = lane & 15;

    __shared__ __align__(16) unsigned short sS[NPIX * SPITCH]; // 18944 B
    __shared__ __align__(16) unsigned short sR[8224];          // 16448 B region
    __shared__ int     s_lbp[9 * NPIX];  // packed gather params
    __shared__ __half2 s_wp [9 * NPIX * 2]; // folded weights fp16x4

    // Overlays: som (864 fl) at sS base; pass-1 dbuf = sR[0..4080),[4080..8160);
    // pass-2 bf16 tile = sR as words[0..3399], overhang zero-guard [3400..4111].
    float* som  = reinterpret_cast<float*>(sS);
    unsigned short* bufA = sR;
    unsigned short* bufB = sR + 4080;

    const size_t xb_base = (size_t)b * CIN * HW;
    const float* gx_base = x + xb_base;

    // ---- pass-2 staging precompute: entry n = t+i*512 over 3200 (rc,slot) ----
    // packed: lword(12b) | slot(4b)<<12 | goff(12b)<<16 ; -1 = inactive
    int stg[7];
#pragma unroll
    for (int i = 0; i < 7; ++i) {
        int n = t + i * 512;
        if (n < 3200) {
            int slot = n / 200;              // 0..15 (channel pair)
            int rc   = n - slot * 200;       // 0..199 (r*40+c)
            int r    = rc / 40;
            int c    = rc - r * 40;
            int gy   = min(max(h - 2 + r, 0), HH - 1);
            int gx   = min(max(w0 - 4 + c, 0), WW - 1);
            stg[i] = (rc * TPW + slot) | (slot << 12) | ((gy * WW + gx) << 16);
        } else stg[i] = -1;
    }

    // ================= Pass 1: om-conv (bf16 tile, b128 frags) =================
    {
        f32x4 accOm = (f32x4)(0.f);
        const int mfp = (wv >> 1) & 1;   // M-frag (o block of 16)
        const int nfp = wv & 1;          // N-frag (pixel block of 16)
        const int p   = nfp * 16 + lm;   // pixel 0..31
        const bf16x8* wOmV = reinterpret_cast<const bf16x8*>(wOmA);

        auto stage1 = [&](int cc, unsigned short* dst) {
            const float* gch = gx_base + (size_t)cc * 32 * HW;
#pragma unroll
            for (int i = 0; i < 7; ++i) {
                int e = t + i * 512;
                if (e < 3264) {
                    int cl  = e / 102;
                    int rc  = e - cl * 102;
                    int row = rc / 34;
                    int col = rc - row * 34;
                    int gy  = h - 1 + row;
                    int gxx = w0 - 1 + col;
                    float v = 0.f;
                    if (gy >= 0 && gy < HH && (unsigned)gxx < WW)
                        v = gch[cl * HW + gy * WW + gxx];
                    dst[rc * XP1 + cl] = f2bf(v);
                }
            }
        };

        stage1(0, bufA);
        __syncthreads();
        for (int cc = 0; cc < 8; ++cc) {
            unsigned short* cur = (cc & 1) ? bufB : bufA;
            unsigned short* nxt = (cc & 1) ? bufA : bufB;
            if (cc < 7) stage1(cc + 1, nxt);
#pragma unroll
            for (int tap = 0; tap < 9; ++tap) {
                int kh = tap / 3, kw = tap % 3;
                bf16x8 bfr = *reinterpret_cast<const bf16x8*>(
                    &cur[(kh * 34 + p + kw) * XP1 + lq * 8]);
                bf16x8 af = wOmV[(((tap * 8 + cc) * 4 + lq) * 32) + mfp * 16 + lm];
                accOm = __builtin_amdgcn_mfma_f32_16x16x32_bf16(af, bfr, accOm, 0, 0, 0);
            }
            __syncthreads();
        }

        if (wv < 4) {
#pragma unroll
            for (int r = 0; r < 4; ++r) {
                int o = mfp * 16 + lq * 4 + r;
                if (o < OMC)
                    som[o * NPIX + p] = accOm[r] + b_om[o];
            }
        }
    }
    __syncthreads();           // som visible; sR free

    // ---- prologue: issue chunk-0 staging loads, compute params, write tile ----
    float L0[7], L1[7];
    {
        const float* gch = gx_base;
#pragma unroll
        for (int i = 0; i < 7; ++i)
            if (stg[i] >= 0) {
                int sl = (stg[i] >> 12) & 0xF;
                int go = (stg[i] >> 16) & 0xFFF;
                L0[i] = gch[(size_t)(2 * sl) * HW + go];
                L1[i] = gch[(size_t)(2 * sl + 1) * HW + go];
            }
    }

    // zero the sR overhang words [3400, 4112): read by weight-0 corner loads,
    // never staged. Leftover LDS here can decode as bf16 NaN/Inf -> 0*NaN=NaN
    // (the R10 replay-only failure). Zero once; stays zero all chunks.
    {
        unsigned int* tWw = reinterpret_cast<unsigned int*>(sR);
        for (int i = t; i < 712; i += 512) tWw[3400 + i] = 0u;
    }

    if (t < 9 * NPIX) {
        int tap = t >> 5;
        int pix = t & 31;
        float dy = som[(2 * tap) * NPIX + pix];
        float dx = som[(2 * tap + 1) * NPIX + pix];
        float mv = som[(18 + tap) * NPIX + pix];
        float m  = 1.f / (1.f + expf(-mv));
        float py = (float)(h - 1 + tap / 3) + dy;
        float px = (float)(w0 + pix - 1 + tap % 3) + dx;
        float y0f = floorf(py), x0f = floorf(px);
        float wy1 = py - y0f, wx1 = px - x0f;
        float wy0 = 1.f - wy1, wx0 = 1.f - wx1;
        int y0 = (int)y0f, x0 = (int)x0f;
        int y1 = y0 + 1, x1 = x0 + 1;
        bool yv0 = (y0 >= 0) && (y0 < HH);
        bool yv1 = (y1 >= 0) && (y1 < HH);
        bool xv0 = (x0 >= 0) && (x0 < WW);
        bool xv1 = (x1 >= 0) && (x1 < WW);
        int yc0 = min(max(y0, 0), HH - 1), yc1 = min(max(y1, 0), HH - 1);
        int xc0 = min(max(x0, 0), WW - 1), xc1 = min(max(x1, 0), WW - 1);
        float wwx = (yv0 && xv0) ? wy0 * wx0 * m : 0.f;
        float wwy = (yv0 && xv1) ? wy0 * wx1 * m : 0.f;
        float wwz = (yv1 && xv0) ? wy1 * wx0 * m : 0.f;
        float www = (yv1 && xv1) ? wy1 * wx1 * m : 0.f;
        // fold clamp-duplicate corners into weights (exact: duplicated coord)
        if (xc1 == xc0) { wwx += wwy; wwy = 0.f; wwz += www; www = 0.f; }
        if (yc1 == yc0) { wwx += wwz; wwz = 0.f; wwy += www; www = 0.f; }
        bool inT = (yc0 >= h - 2) && (yc1 <= h + 2) &&
                   (xc0 >= w0 - 4) && (xc1 <= w0 + 35);
        int lb = (yc0 - (h - 2)) * 40 + (xc0 - (w0 - 4));
        int pk = (lb & 0xFF) | ((xc1 - xc0) << 8) | ((yc1 - yc0) << 9)
               | ((yc0 * WW + xc0) << 10);
        if (!inT) pk |= (int)0x80000000;
        s_lbp[t] = pk;
        s_wp[2 * t]     = __floats2half2_rn(wwx, wwy);
        s_wp[2 * t + 1] = __floats2half2_rn(wwz, www);
    }
    {   // write chunk-0 tile (waits staged loads)
        unsigned int* tWw = reinterpret_cast<unsigned int*>(sR);
#pragma unroll
        for (int i = 0; i < 7; ++i)
            if (stg[i] >= 0)
                tWw[stg[i] & 0xFFF] =
                    f2bf(L0[i]) | ((unsigned int)f2bf(L1[i]) << 16);
    }
    __syncthreads();           // params + chunk-0 tile + zero-guard ready

    // ================= Pass 2: main deform GEMM =================
    f32x4 acc[2][2];
#pragma unroll
    for (int i = 0; i < 2; ++i)
#pragma unroll
        for (int j = 0; j < 2; ++j)
            acc[i][j] = (f32x4)(0.f);

    const int pix  = t >> 4;             // 0..31 gather pixel
    const int slot = t & 15;             // 0..15 channel-pair slot
    const unsigned int* tW = reinterpret_cast<const unsigned int*>(sR);

    for (int ch = 0; ch < 8; ++ch) {
        // ---- gather: 4 packed b32 corner reads per tap (2 channels each) ----
#pragma unroll 3
        for (int tap = 0; tap < 9; ++tap) {
            int idx = tap * NPIX + pix;
            int pk  = s_lbp[idx];
            float2 wab = __half22float2(s_wp[2 * idx]);
            float2 wcd = __half22float2(s_wp[2 * idx + 1]);
            float v0, v1;
            if (pk >= 0) {
                int base = (pk & 0xFF) * TPW + slot;
                unsigned int a00 = tW[base];
                unsigned int a01 = tW[base + TPW];
                unsigned int a10 = tW[base + 40 * TPW];
                unsigned int a11 = tW[base + 41 * TPW];
                v0 = wab.x * bflo(a00) + wab.y * bflo(a01)
                   + wcd.x * bflo(a10) + wcd.y * bflo(a11);
                v1 = wab.x * bfhi(a00) + wab.y * bfhi(a01)
                   + wcd.x * bfhi(a10) + wcd.y * bfhi(a11);
            } else {
                int off00 = (pk >> 10) & 0xFFF;
                int d01 = (pk >> 8) & 1;
                int d10 = ((pk >> 9) & 1) * WW;
                const float* xc = x + xb_base + (size_t)(ch * 32 + 2 * slot) * HW;
                v0 = wab.x * xc[off00]       + wab.y * xc[off00 + d01]
                   + wcd.x * xc[off00 + d10] + wcd.y * xc[off00 + d10 + d01];
                xc += HW;
                v1 = wab.x * xc[off00]       + wab.y * xc[off00 + d01]
                   + wcd.x * xc[off00 + d10] + wcd.y * xc[off00 + d10 + d01];
            }
            *reinterpret_cast<unsigned int*>(
                &sS[pix * SPITCH + tap * 32 + 2 * slot]) =
                f2bf(v0) | ((unsigned int)f2bf(v1) << 16);
        }
        __syncthreads();                  // sS ready; tile consumed

        // ---- issue next chunk's staging loads (hide under MFMA) ----
        if (ch < 7) {
            const float* gch = gx_base + (size_t)(ch + 1) * 32 * HW;
#pragma unroll
            for (int i = 0; i < 7; ++i)
                if (stg[i] >= 0) {
                    int sl = (stg[i] >> 12) & 0xF;
                    int go = (stg[i] >> 16) & 0xFFF;
                    L0[i] = gch[(size_t)(2 * sl) * HW + go];
                    L1[i] = gch[(size_t)(2 * sl + 1) * HW + go];
                }
        }

        // ---- MFMA: wave wv computes o in [wv*32, wv*32+32) ----
        const int kb_base = ch * 36;
        const bf16x8* wAv = reinterpret_cast<const bf16x8*>(wA);
#pragma unroll 1
        for (int ks = 0; ks < 9; ++ks) {
            bf16x8 bfr[2];
#pragma unroll
            for (int nf = 0; nf < 2; ++nf)
                bfr[nf] = *reinterpret_cast<const bf16x8*>(
                    &sS[(nf * 16 + lm) * SPITCH + ks * 32 + lq * 8]);
#pragma unroll
            for (int mf = 0; mf < 2; ++mf) {
                int o  = wv * 32 + mf * 16 + lm;
                int kb = kb_base + ks * 4 + lq;
                bf16x8 af = wAv[(size_t)kb * 256 + o];
#pragma unroll
                for (int nf = 0; nf < 2; ++nf)
                    acc[mf][nf] = __builtin_amdgcn_mfma_f32_16x16x32_bf16(
                        af, bfr[nf], acc[mf][nf], 0, 0, 0);
            }
        }

        // ---- write next tile (loads have landed under MFMA) ----
        if (ch < 7) {
            unsigned int* tWw = reinterpret_cast<unsigned int*>(sR);
#pragma unroll
            for (int i = 0; i < 7; ++i)
                if (stg[i] >= 0)
                    tWw[stg[i] & 0xFFF] =
                        f2bf(L0[i]) | ((unsigned int)f2bf(L1[i]) << 16);
        }
        __syncthreads();        // sS free + next tile ready
    }

    // ---- epilogue: D row = lq*4 + r, col = lm ----
#pragma unroll
    for (int mf = 0; mf < 2; ++mf) {
#pragma unroll
        for (int r = 0; r < 4; ++r) {
            int o = wv * 32 + mf * 16 + lq * 4 + r;
            float bo = b_dc[o];
#pragma unroll
            for (int nf = 0; nf < 2; ++nf) {
                int p = nf * 16 + lm;
                out[((size_t)(b * 256 + o)) * HW + h * WW + w0 + p] = acc[mf][nf][r] + bo;
            }
        }
    }
}

extern "C" void kernel_launch(void* const* d_in, const int* in_sizes, int n_in,
                              void* d_out, int out_size, void* d_ws, size_t ws_size,
                              hipStream_t stream) {
    const float* x    = (const float*)d_in[0];
    const float* w_om = (const float*)d_in[1];
    const float* b_om = (const float*)d_in[2];
    const float* w_dc = (const float*)d_in[3];
    const float* b_dc = (const float*)d_in[4];
    float* out = (float*)d_out;

    unsigned short* wA   = (unsigned short*)d_ws;                    // 1,179,648 B
    unsigned short* wOmA = (unsigned short*)((char*)d_ws + 1179648); //   147,456 B

    wprep_kernel<<<(256 * KTOT) / 256, 256, 0, stream>>>(w_dc, wA);
    womprep_kernel<<<73728 / 256, 256, 0, stream>>>(w_om, wOmA);
    deform_mfma_kernel<<<BB * HH * 2, 512, 0, stream>>>(x, wOmA, b_om, wA, b_dc, out);
}

// Round 12
// 162.741 us; speedup vs baseline: 1.2823x; 1.2823x over previous
//
#include <hip/hip_runtime.h>
#include <hip/hip_bf16.h>
#include <hip/hip_fp16.h>
#include <math.h>

// Problem constants
#define BB   8
#define CIN  256
#define HH   64
#define WW   64
#define OMC  27          // 3*K offset/mask channels
#define HW   (HH*WW)
#define KTOT (CIN*9)     // 2304 GEMM K
#define NPIX 32          // pixels per block (N tile)
#define SPITCH 296       // LDS sample row pitch in halves (288 + 8 pad)
#define XP1    40        // pass-1 bf16 tile ch pitch (halves)
#define TPW    17        // pass-2 tile words per rc entry (32ch bf16 + 1 pad word)

typedef short bf16x8 __attribute__((ext_vector_type(8)));
typedef float f32x4  __attribute__((ext_vector_type(4)));

__device__ __forceinline__ unsigned short f2bf(float f) {
    union { float f; unsigned int u; } v; v.f = f;
    unsigned int r = v.u + 0x7FFFu + ((v.u >> 16) & 1u);   // RNE
    return (unsigned short)(r >> 16);
}
__device__ __forceinline__ float bflo(unsigned int a) {
    union { unsigned int u; float f; } c; c.u = a << 16; return c.f;
}
__device__ __forceinline__ float bfhi(unsigned int a) {
    union { unsigned int u; float f; } c; c.u = a & 0xFFFF0000u; return c.f;
}

// ---------------------------------------------------------------------------
// Kernel 0a: w_dc (fp32 [o][c*9+tap]) -> bf16 wA, TAP-MAJOR chunk-local k:
//   k' = (c>>5)*288 + tap*32 + (c&31);  wA[k'>>3][o][k'&7]
// ---------------------------------------------------------------------------
__global__ __launch_bounds__(256) void wprep_kernel(
    const float* __restrict__ w_dc, unsigned short* __restrict__ wA)
{
    int e = blockIdx.x * 256 + threadIdx.x;          // 256*2304 elements
    int o = e / KTOT;
    int k = e - o * KTOT;
    int c   = k / 9;
    int tap = k - c * 9;
    int kp  = (c >> 5) * 288 + tap * 32 + (c & 31);
    wA[((size_t)(kp >> 3) * 256 + o) * 8 + (kp & 7)] = f2bf(w_dc[e]);
}

// ---------------------------------------------------------------------------
// Kernel 0b: w_om (fp32 [27][256][9]) -> bf16 padded/swizzled:
// wOmA[(((tap*8+cc)*4 + cb)*32 + o)*8 + j], channel c = cc*32+cb*8+j, o<32pad.
// ---------------------------------------------------------------------------
__global__ __launch_bounds__(256) void womprep_kernel(
    const float* __restrict__ w_om, unsigned short* __restrict__ wOmA)
{
    int e = blockIdx.x * 256 + threadIdx.x;          // 73728
    int j  = e & 7;
    int t1 = e >> 3;
    int o  = t1 & 31;
    int t2 = t1 >> 5;
    int cb = t2 & 3;
    int t3 = t2 >> 2;
    int cc = t3 & 7;
    int tap = t3 >> 3;
    int c = cc * 32 + cb * 8 + j;
    float v = (o < OMC) ? w_om[(size_t)o * KTOT + c * 9 + tap] : 0.f;
    wOmA[e] = f2bf(v);
}

// ---------------------------------------------------------------------------
// Fused kernel, 512 threads (8 waves). M=256, N=32 pixels, K=2304.
// Pass 1: om-conv from bf16 [rc][ch] tile (dbuf, b128 frags).
// Pass 2: bilinear gather from CHANNEL-INTERLEAVED bf16 tile
//         ([rc][32ch], 17-word pitch, reg-staged T14-style), 4 b32/tap/2ch,
//         fp16-packed folded weights, bf16 MFMA GEMM.
// launch_bounds (512,4): 128-VGPR budget -- R11's (512,8) forced 32 VGPRs and
// spilled the staging arrays to scratch (+170MB FETCH, +200MB WRITE).
// ---------------------------------------------------------------------------
__global__ __launch_bounds__(512, 4) void deform_mfma_kernel(
    const float* __restrict__ x, const unsigned short* __restrict__ wOmA,
    const float* __restrict__ b_om,
    const unsigned short* __restrict__ wA, const float* __restrict__ b_dc,
    float* __restrict__ out)
{
    const int bid  = blockIdx.x;         // b*128 + h*2 + wt
    const int b    = bid >> 7;
    const int h    = (bid >> 1) & 63;
    const int w0   = (bid & 1) * NPIX;
    const int t    = threadIdx.x;
    const int wv   = t >> 6;             // wave 0..7
    const int lane = t & 63;
    const int lq   = lane >> 4;          // k-quarter
    const int lm   = lane & 15;

    __shared__ __align__(16) unsigned short sS[NPIX * SPITCH]; // 18944 B
    __shared__ __align__(16) unsigned short sR[8224];          // 16448 B region
    __shared__ int     s_lbp[9 * NPIX];  // packed gather params
    __shared__ __half2 s_wp [9 * NPIX * 2]; // folded weights fp16x4

    // Overlays: som (864 fl) at sS base; pass-1 dbuf = sR[0..4080),[4080..8160);
    // pass-2 bf16 tile = sR as words[0..3399], overhang zero-guard [3400..4111].
    float* som  = reinterpret_cast<float*>(sS);
    unsigned short* bufA = sR;
    unsigned short* bufB = sR + 4080;

    const size_t xb_base = (size_t)b * CIN * HW;
    const float* gx_base = x + xb_base;

    // ---- pass-2 staging precompute: entry n = t+i*512 over 3200 (rc,slot) ----
    // packed: lword(12b) | slot(4b)<<12 | goff(12b)<<16 ; -1 = inactive
    int stg[7];
#pragma unroll
    for (int i = 0; i < 7; ++i) {
        int n = t + i * 512;
        if (n < 3200) {
            int slot = n / 200;              // 0..15 (channel pair)
            int rc   = n - slot * 200;       // 0..199 (r*40+c)
            int r    = rc / 40;
            int c    = rc - r * 40;
            int gy   = min(max(h - 2 + r, 0), HH - 1);
            int gx   = min(max(w0 - 4 + c, 0), WW - 1);
            stg[i] = (rc * TPW + slot) | (slot << 12) | ((gy * WW + gx) << 16);
        } else stg[i] = -1;
    }

    // ================= Pass 1: om-conv (bf16 tile, b128 frags) =================
    {
        f32x4 accOm = (f32x4)(0.f);
        const int mfp = (wv >> 1) & 1;   // M-frag (o block of 16)
        const int nfp = wv & 1;          // N-frag (pixel block of 16)
        const int p   = nfp * 16 + lm;   // pixel 0..31
        const bf16x8* wOmV = reinterpret_cast<const bf16x8*>(wOmA);

        auto stage1 = [&](int cc, unsigned short* dst) {
            const float* gch = gx_base + (size_t)cc * 32 * HW;
#pragma unroll
            for (int i = 0; i < 7; ++i) {
                int e = t + i * 512;
                if (e < 3264) {
                    int cl  = e / 102;
                    int rc  = e - cl * 102;
                    int row = rc / 34;
                    int col = rc - row * 34;
                    int gy  = h - 1 + row;
                    int gxx = w0 - 1 + col;
                    float v = 0.f;
                    if (gy >= 0 && gy < HH && (unsigned)gxx < WW)
                        v = gch[cl * HW + gy * WW + gxx];
                    dst[rc * XP1 + cl] = f2bf(v);
                }
            }
        };

        stage1(0, bufA);
        __syncthreads();
        for (int cc = 0; cc < 8; ++cc) {
            unsigned short* cur = (cc & 1) ? bufB : bufA;
            unsigned short* nxt = (cc & 1) ? bufA : bufB;
            if (cc < 7) stage1(cc + 1, nxt);
#pragma unroll
            for (int tap = 0; tap < 9; ++tap) {
                int kh = tap / 3, kw = tap % 3;
                bf16x8 bfr = *reinterpret_cast<const bf16x8*>(
                    &cur[(kh * 34 + p + kw) * XP1 + lq * 8]);
                bf16x8 af = wOmV[(((tap * 8 + cc) * 4 + lq) * 32) + mfp * 16 + lm];
                accOm = __builtin_amdgcn_mfma_f32_16x16x32_bf16(af, bfr, accOm, 0, 0, 0);
            }
            __syncthreads();
        }

        if (wv < 4) {
#pragma unroll
            for (int r = 0; r < 4; ++r) {
                int o = mfp * 16 + lq * 4 + r;
                if (o < OMC)
                    som[o * NPIX + p] = accOm[r] + b_om[o];
            }
        }
    }
    __syncthreads();           // som visible; sR free

    // ---- prologue: issue chunk-0 staging loads, compute params, write tile ----
    float L0[7], L1[7];
    {
        const float* gch = gx_base;
#pragma unroll
        for (int i = 0; i < 7; ++i)
            if (stg[i] >= 0) {
                int sl = (stg[i] >> 12) & 0xF;
                int go = (stg[i] >> 16) & 0xFFF;
                L0[i] = gch[(size_t)(2 * sl) * HW + go];
                L1[i] = gch[(size_t)(2 * sl + 1) * HW + go];
            }
    }

    // zero the sR overhang words [3400, 4112): read by weight-0 corner loads,
    // never staged. Leftover LDS here can decode as bf16 NaN/Inf -> 0*NaN=NaN
    // (the R10 replay-only failure). Zero once; stays zero all chunks.
    {
        unsigned int* tWw = reinterpret_cast<unsigned int*>(sR);
        for (int i = t; i < 712; i += 512) tWw[3400 + i] = 0u;
    }

    if (t < 9 * NPIX) {
        int tap = t >> 5;
        int pix = t & 31;
        float dy = som[(2 * tap) * NPIX + pix];
        float dx = som[(2 * tap + 1) * NPIX + pix];
        float mv = som[(18 + tap) * NPIX + pix];
        float m  = 1.f / (1.f + expf(-mv));
        float py = (float)(h - 1 + tap / 3) + dy;
        float px = (float)(w0 + pix - 1 + tap % 3) + dx;
        float y0f = floorf(py), x0f = floorf(px);
        float wy1 = py - y0f, wx1 = px - x0f;
        float wy0 = 1.f - wy1, wx0 = 1.f - wx1;
        int y0 = (int)y0f, x0 = (int)x0f;
        int y1 = y0 + 1, x1 = x0 + 1;
        bool yv0 = (y0 >= 0) && (y0 < HH);
        bool yv1 = (y1 >= 0) && (y1 < HH);
        bool xv0 = (x0 >= 0) && (x0 < WW);
        bool xv1 = (x1 >= 0) && (x1 < WW);
        int yc0 = min(max(y0, 0), HH - 1), yc1 = min(max(y1, 0), HH - 1);
        int xc0 = min(max(x0, 0), WW - 1), xc1 = min(max(x1, 0), WW - 1);
        float wwx = (yv0 && xv0) ? wy0 * wx0 * m : 0.f;
        float wwy = (yv0 && xv1) ? wy0 * wx1 * m : 0.f;
        float wwz = (yv1 && xv0) ? wy1 * wx0 * m : 0.f;
        float www = (yv1 && xv1) ? wy1 * wx1 * m : 0.f;
        // fold clamp-duplicate corners into weights (exact: duplicated coord)
        if (xc1 == xc0) { wwx += wwy; wwy = 0.f; wwz += www; www = 0.f; }
        if (yc1 == yc0) { wwx += wwz; wwz = 0.f; wwy += www; www = 0.f; }
        bool inT = (yc0 >= h - 2) && (yc1 <= h + 2) &&
                   (xc0 >= w0 - 4) && (xc1 <= w0 + 35);
        int lb = (yc0 - (h - 2)) * 40 + (xc0 - (w0 - 4));
        int pk = (lb & 0xFF) | ((xc1 - xc0) << 8) | ((yc1 - yc0) << 9)
               | ((yc0 * WW + xc0) << 10);
        if (!inT) pk |= (int)0x80000000;
        s_lbp[t] = pk;
        s_wp[2 * t]     = __floats2half2_rn(wwx, wwy);
        s_wp[2 * t + 1] = __floats2half2_rn(wwz, www);
    }
    {   // write chunk-0 tile (waits staged loads)
        unsigned int* tWw = reinterpret_cast<unsigned int*>(sR);
#pragma unroll
        for (int i = 0; i < 7; ++i)
            if (stg[i] >= 0)
                tWw[stg[i] & 0xFFF] =
                    f2bf(L0[i]) | ((unsigned int)f2bf(L1[i]) << 16);
    }
    __syncthreads();           // params + chunk-0 tile + zero-guard ready

    // ================= Pass 2: main deform GEMM =================
    f32x4 acc[2][2];
#pragma unroll
    for (int i = 0; i < 2; ++i)
#pragma unroll
        for (int j = 0; j < 2; ++j)
            acc[i][j] = (f32x4)(0.f);

    const int pix  = t >> 4;             // 0..31 gather pixel
    const int slot = t & 15;             // 0..15 channel-pair slot
    const unsigned int* tW = reinterpret_cast<const unsigned int*>(sR);

    for (int ch = 0; ch < 8; ++ch) {
        // ---- gather: 4 packed b32 corner reads per tap (2 channels each) ----
#pragma unroll 3
        for (int tap = 0; tap < 9; ++tap) {
            int idx = tap * NPIX + pix;
            int pk  = s_lbp[idx];
            float2 wab = __half22float2(s_wp[2 * idx]);
            float2 wcd = __half22float2(s_wp[2 * idx + 1]);
            float v0, v1;
            if (pk >= 0) {
                int base = (pk & 0xFF) * TPW + slot;
                unsigned int a00 = tW[base];
                unsigned int a01 = tW[base + TPW];
                unsigned int a10 = tW[base + 40 * TPW];
                unsigned int a11 = tW[base + 41 * TPW];
                v0 = wab.x * bflo(a00) + wab.y * bflo(a01)
                   + wcd.x * bflo(a10) + wcd.y * bflo(a11);
                v1 = wab.x * bfhi(a00) + wab.y * bfhi(a01)
                   + wcd.x * bfhi(a10) + wcd.y * bfhi(a11);
            } else {
                int off00 = (pk >> 10) & 0xFFF;
                int d01 = (pk >> 8) & 1;
                int d10 = ((pk >> 9) & 1) * WW;
                const float* xc = x + xb_base + (size_t)(ch * 32 + 2 * slot) * HW;
                v0 = wab.x * xc[off00]       + wab.y * xc[off00 + d01]
                   + wcd.x * xc[off00 + d10] + wcd.y * xc[off00 + d10 + d01];
                xc += HW;
                v1 = wab.x * xc[off00]       + wab.y * xc[off00 + d01]
                   + wcd.x * xc[off00 + d10] + wcd.y * xc[off00 + d10 + d01];
            }
            *reinterpret_cast<unsigned int*>(
                &sS[pix * SPITCH + tap * 32 + 2 * slot]) =
                f2bf(v0) | ((unsigned int)f2bf(v1) << 16);
        }
        __syncthreads();                  // sS ready; tile consumed

        // ---- issue next chunk's staging loads (hide under MFMA) ----
        if (ch < 7) {
            const float* gch = gx_base + (size_t)(ch + 1) * 32 * HW;
#pragma unroll
            for (int i = 0; i < 7; ++i)
                if (stg[i] >= 0) {
                    int sl = (stg[i] >> 12) & 0xF;
                    int go = (stg[i] >> 16) & 0xFFF;
                    L0[i] = gch[(size_t)(2 * sl) * HW + go];
                    L1[i] = gch[(size_t)(2 * sl + 1) * HW + go];
                }
        }

        // ---- MFMA: wave wv computes o in [wv*32, wv*32+32) ----
        const int kb_base = ch * 36;
        const bf16x8* wAv = reinterpret_cast<const bf16x8*>(wA);
#pragma unroll 1
        for (int ks = 0; ks < 9; ++ks) {
            bf16x8 bfr[2];
#pragma unroll
            for (int nf = 0; nf < 2; ++nf)
                bfr[nf] = *reinterpret_cast<const bf16x8*>(
                    &sS[(nf * 16 + lm) * SPITCH + ks * 32 + lq * 8]);
#pragma unroll
            for (int mf = 0; mf < 2; ++mf) {
                int o  = wv * 32 + mf * 16 + lm;
                int kb = kb_base + ks * 4 + lq;
                bf16x8 af = wAv[(size_t)kb * 256 + o];
#pragma unroll
                for (int nf = 0; nf < 2; ++nf)
                    acc[mf][nf] = __builtin_amdgcn_mfma_f32_16x16x32_bf16(
                        af, bfr[nf], acc[mf][nf], 0, 0, 0);
            }
        }

        // ---- write next tile (loads have landed under MFMA) ----
        if (ch < 7) {
            unsigned int* tWw = reinterpret_cast<unsigned int*>(sR);
#pragma unroll
            for (int i = 0; i < 7; ++i)
                if (stg[i] >= 0)
                    tWw[stg[i] & 0xFFF] =
                        f2bf(L0[i]) | ((unsigned int)f2bf(L1[i]) << 16);
        }
        __syncthreads();        // sS free + next tile ready
    }

    // ---- epilogue: D row = lq*4 + r, col = lm ----
#pragma unroll
    for (int mf = 0; mf < 2; ++mf) {
#pragma unroll
        for (int r = 0; r < 4; ++r) {
            int o = wv * 32 + mf * 16 + lq * 4 + r;
            float bo = b_dc[o];
#pragma unroll
            for (int nf = 0; nf < 2; ++nf) {
                int p = nf * 16 + lm;
                out[((size_t)(b * 256 + o)) * HW + h * WW + w0 + p] = acc[mf][nf][r] + bo;
            }
        }
    }
}

extern "C" void kernel_launch(void* const* d_in, const int* in_sizes, int n_in,
                              void* d_out, int out_size, void* d_ws, size_t ws_size,
                              hipStream_t stream) {
    const float* x    = (const float*)d_in[0];
    const float* w_om = (const float*)d_in[1];
    const float* b_om = (const float*)d_in[2];
    const float* w_dc = (const float*)d_in[3];
    const float* b_dc = (const float*)d_in[4];
    float* out = (float*)d_out;

    unsigned short* wA   = (unsigned short*)d_ws;                    // 1,179,648 B
    unsigned short* wOmA = (unsigned short*)((char*)d_ws + 1179648); //   147,456 B

    wprep_kernel<<<(256 * KTOT) / 256, 256, 0, stream>>>(w_dc, wA);
    womprep_kernel<<<73728 / 256, 256, 0, stream>>>(w_om, wOmA);
    deform_mfma_kernel<<<BB * HH * 2, 512, 0, stream>>>(x, wOmA, b_om, wA, b_dc, out);
}

// Round 13
// 152.226 us; speedup vs baseline: 1.3709x; 1.0691x over previous
//
#include <hip/hip_runtime.h>
#include <hip/hip_bf16.h>
#include <hip/hip_fp16.h>
#include <math.h>

// Problem constants
#define BB   8
#define CIN  256
#define HH   64
#define WW   64
#define OMC  27          // 3*K offset/mask channels
#define HW   (HH*WW)
#define KTOT (CIN*9)     // 2304 GEMM K
#define NPIX 32          // pixels per block (N tile)
#define SPITCH 296       // LDS sample row pitch in halves (288 + 8 pad)
#define XP1    40        // pass-1 bf16 tile ch pitch (halves)
#define TPW    17        // pass-2 tile words per rc entry (32ch bf16 + 1 pad word)

typedef short bf16x8 __attribute__((ext_vector_type(8)));
typedef float f32x4  __attribute__((ext_vector_type(4)));

__device__ __forceinline__ unsigned short f2bf(float f) {
    union { float f; unsigned int u; } v; v.f = f;
    unsigned int r = v.u + 0x7FFFu + ((v.u >> 16) & 1u);   // RNE
    return (unsigned short)(r >> 16);
}
__device__ __forceinline__ float bflo(unsigned int a) {
    union { unsigned int u; float f; } c; c.u = a << 16; return c.f;
}
__device__ __forceinline__ float bfhi(unsigned int a) {
    union { unsigned int u; float f; } c; c.u = a & 0xFFFF0000u; return c.f;
}

// ---------------------------------------------------------------------------
// Kernel 0a: w_dc (fp32 [o][c*9+tap]) -> bf16 wA, TAP-MAJOR chunk-local k:
//   k' = (c>>5)*288 + tap*32 + (c&31);  wA[k'>>3][o][k'&7]
// ---------------------------------------------------------------------------
__global__ __launch_bounds__(256) void wprep_kernel(
    const float* __restrict__ w_dc, unsigned short* __restrict__ wA)
{
    int e = blockIdx.x * 256 + threadIdx.x;          // 256*2304 elements
    int o = e / KTOT;
    int k = e - o * KTOT;
    int c   = k / 9;
    int tap = k - c * 9;
    int kp  = (c >> 5) * 288 + tap * 32 + (c & 31);
    wA[((size_t)(kp >> 3) * 256 + o) * 8 + (kp & 7)] = f2bf(w_dc[e]);
}

// ---------------------------------------------------------------------------
// Kernel 0b: w_om (fp32 [27][256][9]) -> bf16 padded/swizzled:
// wOmA[(((tap*8+cc)*4 + cb)*32 + o)*8 + j], channel c = cc*32+cb*8+j, o<32pad.
// ---------------------------------------------------------------------------
__global__ __launch_bounds__(256) void womprep_kernel(
    const float* __restrict__ w_om, unsigned short* __restrict__ wOmA)
{
    int e = blockIdx.x * 256 + threadIdx.x;          // 73728
    int j  = e & 7;
    int t1 = e >> 3;
    int o  = t1 & 31;
    int t2 = t1 >> 5;
    int cb = t2 & 3;
    int t3 = t2 >> 2;
    int cc = t3 & 7;
    int tap = t3 >> 3;
    int c = cc * 32 + cb * 8 + j;
    float v = (o < OMC) ? w_om[(size_t)o * KTOT + c * 9 + tap] : 0.f;
    wOmA[e] = f2bf(v);
}

// ---------------------------------------------------------------------------
// Fused kernel, 512 threads (8 waves). M=256, N=32 pixels, K=2304.
// XCD swizzle: grid = 1024 = 8 batches x 128; consecutive hardware blockIdx
// round-robin across the 8 XCDs, so obid = (bid&7)<<7 | (bid>>3) puts ALL
// 128 blocks of batch b on XCD b -> x[b] (4.2MB) streams through that XCD's
// private 4MB L2 instead of 8x HBM re-fetch (R12: FETCH=238MB = 7x input).
// Pass 1: om-conv from bf16 [rc][ch] tile (dbuf, b128 frags).
// Pass 2: bilinear gather from CHANNEL-INTERLEAVED bf16 tile
//         ([rc][32ch], 17-word pitch, reg-staged T14-style), 4 b32/tap/2ch,
//         fp16-packed folded weights, bf16 MFMA GEMM.
// ---------------------------------------------------------------------------
__global__ __launch_bounds__(512, 4) void deform_mfma_kernel(
    const float* __restrict__ x, const unsigned short* __restrict__ wOmA,
    const float* __restrict__ b_om,
    const unsigned short* __restrict__ wA, const float* __restrict__ b_dc,
    float* __restrict__ out)
{
    const int rawb = blockIdx.x;
    const int obid = ((rawb & 7) << 7) | (rawb >> 3);   // batch-per-XCD swizzle
    const int b    = obid >> 7;
    const int h    = (obid >> 1) & 63;
    const int w0   = (obid & 1) * NPIX;
    const int t    = threadIdx.x;
    const int wv   = t >> 6;             // wave 0..7
    const int lane = t & 63;
    const int lq   = lane >> 4;          // k-quarter
    const int lm   = lane & 15;

    __shared__ __align__(16) unsigned short sS[NPIX * SPITCH]; // 18944 B
    __shared__ __align__(16) unsigned short sR[8224];          // 16448 B region
    __shared__ int     s_lbp[9 * NPIX];  // packed gather params
    __shared__ __half2 s_wp [9 * NPIX * 2]; // folded weights fp16x4

    // Overlays: som (864 fl) at sS base; pass-1 dbuf = sR[0..4080),[4080..8160);
    // pass-2 bf16 tile = sR as words[0..3399], overhang zero-guard [3400..4111].
    float* som  = reinterpret_cast<float*>(sS);
    unsigned short* bufA = sR;
    unsigned short* bufB = sR + 4080;

    const size_t xb_base = (size_t)b * CIN * HW;
    const float* gx_base = x + xb_base;

    // ---- pass-2 staging precompute: entry n = t+i*512 over 3200 (rc,slot) ----
    // packed: lword(12b) | slot(4b)<<12 | goff(12b)<<16 ; -1 = inactive
    int stg[7];
#pragma unroll
    for (int i = 0; i < 7; ++i) {
        int n = t + i * 512;
        if (n < 3200) {
            int slot = n / 200;              // 0..15 (channel pair)
            int rc   = n - slot * 200;       // 0..199 (r*40+c)
            int r    = rc / 40;
            int c    = rc - r * 40;
            int gy   = min(max(h - 2 + r, 0), HH - 1);
            int gx   = min(max(w0 - 4 + c, 0), WW - 1);
            stg[i] = (rc * TPW + slot) | (slot << 12) | ((gy * WW + gx) << 16);
        } else stg[i] = -1;
    }

    // ================= Pass 1: om-conv (bf16 tile, b128 frags) =================
    {
        f32x4 accOm = (f32x4)(0.f);
        const int mfp = (wv >> 1) & 1;   // M-frag (o block of 16)
        const int nfp = wv & 1;          // N-frag (pixel block of 16)
        const int p   = nfp * 16 + lm;   // pixel 0..31
        const bf16x8* wOmV = reinterpret_cast<const bf16x8*>(wOmA);

        auto stage1 = [&](int cc, unsigned short* dst) {
            const float* gch = gx_base + (size_t)cc * 32 * HW;
#pragma unroll
            for (int i = 0; i < 7; ++i) {
                int e = t + i * 512;
                if (e < 3264) {
                    int cl  = e / 102;
                    int rc  = e - cl * 102;
                    int row = rc / 34;
                    int col = rc - row * 34;
                    int gy  = h - 1 + row;
                    int gxx = w0 - 1 + col;
                    float v = 0.f;
                    if (gy >= 0 && gy < HH && (unsigned)gxx < WW)
                        v = gch[cl * HW + gy * WW + gxx];
                    dst[rc * XP1 + cl] = f2bf(v);
                }
            }
        };

        stage1(0, bufA);
        __syncthreads();
        for (int cc = 0; cc < 8; ++cc) {
            unsigned short* cur = (cc & 1) ? bufB : bufA;
            unsigned short* nxt = (cc & 1) ? bufA : bufB;
            if (cc < 7) stage1(cc + 1, nxt);
#pragma unroll
            for (int tap = 0; tap < 9; ++tap) {
                int kh = tap / 3, kw = tap % 3;
                bf16x8 bfr = *reinterpret_cast<const bf16x8*>(
                    &cur[(kh * 34 + p + kw) * XP1 + lq * 8]);
                bf16x8 af = wOmV[(((tap * 8 + cc) * 4 + lq) * 32) + mfp * 16 + lm];
                accOm = __builtin_amdgcn_mfma_f32_16x16x32_bf16(af, bfr, accOm, 0, 0, 0);
            }
            __syncthreads();
        }

        if (wv < 4) {
#pragma unroll
            for (int r = 0; r < 4; ++r) {
                int o = mfp * 16 + lq * 4 + r;
                if (o < OMC)
                    som[o * NPIX + p] = accOm[r] + b_om[o];
            }
        }
    }
    __syncthreads();           // som visible; sR free

    // ---- prologue: issue chunk-0 staging loads, compute params, write tile ----
    float L0[7], L1[7];
    {
        const float* gch = gx_base;
#pragma unroll
        for (int i = 0; i < 7; ++i)
            if (stg[i] >= 0) {
                int sl = (stg[i] >> 12) & 0xF;
                int go = (stg[i] >> 16) & 0xFFF;
                L0[i] = gch[(size_t)(2 * sl) * HW + go];
                L1[i] = gch[(size_t)(2 * sl + 1) * HW + go];
            }
    }

    // zero the sR overhang words [3400, 4112): read by weight-0 corner loads,
    // never staged. Leftover LDS here can decode as bf16 NaN/Inf -> 0*NaN=NaN
    // (the R10 replay-only failure). Zero once; stays zero all chunks.
    {
        unsigned int* tWw = reinterpret_cast<unsigned int*>(sR);
        for (int i = t; i < 712; i += 512) tWw[3400 + i] = 0u;
    }

    if (t < 9 * NPIX) {
        int tap = t >> 5;
        int pix = t & 31;
        float dy = som[(2 * tap) * NPIX + pix];
        float dx = som[(2 * tap + 1) * NPIX + pix];
        float mv = som[(18 + tap) * NPIX + pix];
        float m  = 1.f / (1.f + expf(-mv));
        float py = (float)(h - 1 + tap / 3) + dy;
        float px = (float)(w0 + pix - 1 + tap % 3) + dx;
        float y0f = floorf(py), x0f = floorf(px);
        float wy1 = py - y0f, wx1 = px - x0f;
        float wy0 = 1.f - wy1, wx0 = 1.f - wx1;
        int y0 = (int)y0f, x0 = (int)x0f;
        int y1 = y0 + 1, x1 = x0 + 1;
        bool yv0 = (y0 >= 0) && (y0 < HH);
        bool yv1 = (y1 >= 0) && (y1 < HH);
        bool xv0 = (x0 >= 0) && (x0 < WW);
        bool xv1 = (x1 >= 0) && (x1 < WW);
        int yc0 = min(max(y0, 0), HH - 1), yc1 = min(max(y1, 0), HH - 1);
        int xc0 = min(max(x0, 0), WW - 1), xc1 = min(max(x1, 0), WW - 1);
        float wwx = (yv0 && xv0) ? wy0 * wx0 * m : 0.f;
        float wwy = (yv0 && xv1) ? wy0 * wx1 * m : 0.f;
        float wwz = (yv1 && xv0) ? wy1 * wx0 * m : 0.f;
        float www = (yv1 && xv1) ? wy1 * wx1 * m : 0.f;
        // fold clamp-duplicate corners into weights (exact: duplicated coord)
        if (xc1 == xc0) { wwx += wwy; wwy = 0.f; wwz += www; www = 0.f; }
        if (yc1 == yc0) { wwx += wwz; wwz = 0.f; wwy += www; www = 0.f; }
        bool inT = (yc0 >= h - 2) && (yc1 <= h + 2) &&
                   (xc0 >= w0 - 4) && (xc1 <= w0 + 35);
        int lb = (yc0 - (h - 2)) * 40 + (xc0 - (w0 - 4));
        int pk = (lb & 0xFF) | ((xc1 - xc0) << 8) | ((yc1 - yc0) << 9)
               | ((yc0 * WW + xc0) << 10);
        if (!inT) pk |= (int)0x80000000;
        s_lbp[t] = pk;
        s_wp[2 * t]     = __floats2half2_rn(wwx, wwy);
        s_wp[2 * t + 1] = __floats2half2_rn(wwz, www);
    }
    {   // write chunk-0 tile (waits staged loads)
        unsigned int* tWw = reinterpret_cast<unsigned int*>(sR);
#pragma unroll
        for (int i = 0; i < 7; ++i)
            if (stg[i] >= 0)
                tWw[stg[i] & 0xFFF] =
                    f2bf(L0[i]) | ((unsigned int)f2bf(L1[i]) << 16);
    }
    __syncthreads();           // params + chunk-0 tile + zero-guard ready

    // ================= Pass 2: main deform GEMM =================
    f32x4 acc[2][2];
#pragma unroll
    for (int i = 0; i < 2; ++i)
#pragma unroll
        for (int j = 0; j < 2; ++j)
            acc[i][j] = (f32x4)(0.f);

    const int pix  = t >> 4;             // 0..31 gather pixel
    const int slot = t & 15;             // 0..15 channel-pair slot
    const unsigned int* tW = reinterpret_cast<const unsigned int*>(sR);

    for (int ch = 0; ch < 8; ++ch) {
        // ---- gather: 4 packed b32 corner reads per tap (2 channels each) ----
#pragma unroll 3
        for (int tap = 0; tap < 9; ++tap) {
            int idx = tap * NPIX + pix;
            int pk  = s_lbp[idx];
            float2 wab = __half22float2(s_wp[2 * idx]);
            float2 wcd = __half22float2(s_wp[2 * idx + 1]);
            float v0, v1;
            if (pk >= 0) {
                int base = (pk & 0xFF) * TPW + slot;
                unsigned int a00 = tW[base];
                unsigned int a01 = tW[base + TPW];
                unsigned int a10 = tW[base + 40 * TPW];
                unsigned int a11 = tW[base + 41 * TPW];
                v0 = wab.x * bflo(a00) + wab.y * bflo(a01)
                   + wcd.x * bflo(a10) + wcd.y * bflo(a11);
                v1 = wab.x * bfhi(a00) + wab.y * bfhi(a01)
                   + wcd.x * bfhi(a10) + wcd.y * bfhi(a11);
            } else {
                int off00 = (pk >> 10) & 0xFFF;
                int d01 = (pk >> 8) & 1;
                int d10 = ((pk >> 9) & 1) * WW;
                const float* xc = x + xb_base + (size_t)(ch * 32 + 2 * slot) * HW;
                v0 = wab.x * xc[off00]       + wab.y * xc[off00 + d01]
                   + wcd.x * xc[off00 + d10] + wcd.y * xc[off00 + d10 + d01];
                xc += HW;
                v1 = wab.x * xc[off00]       + wab.y * xc[off00 + d01]
                   + wcd.x * xc[off00 + d10] + wcd.y * xc[off00 + d10 + d01];
            }
            *reinterpret_cast<unsigned int*>(
                &sS[pix * SPITCH + tap * 32 + 2 * slot]) =
                f2bf(v0) | ((unsigned int)f2bf(v1) << 16);
        }
        __syncthreads();                  // sS ready; tile consumed

        // ---- issue next chunk's staging loads (hide under MFMA) ----
        if (ch < 7) {
            const float* gch = gx_base + (size_t)(ch + 1) * 32 * HW;
#pragma unroll
            for (int i = 0; i < 7; ++i)
                if (stg[i] >= 0) {
                    int sl = (stg[i] >> 12) & 0xF;
                    int go = (stg[i] >> 16) & 0xFFF;
                    L0[i] = gch[(size_t)(2 * sl) * HW + go];
                    L1[i] = gch[(size_t)(2 * sl + 1) * HW + go];
                }
        }

        // ---- MFMA: wave wv computes o in [wv*32, wv*32+32) ----
        const int kb_base = ch * 36;
        const bf16x8* wAv = reinterpret_cast<const bf16x8*>(wA);
#pragma unroll 1
        for (int ks = 0; ks < 9; ++ks) {
            bf16x8 bfr[2];
#pragma unroll
            for (int nf = 0; nf < 2; ++nf)
                bfr[nf] = *reinterpret_cast<const bf16x8*>(
                    &sS[(nf * 16 + lm) * SPITCH + ks * 32 + lq * 8]);
#pragma unroll
            for (int mf = 0; mf < 2; ++mf) {
                int o  = wv * 32 + mf * 16 + lm;
                int kb = kb_base + ks * 4 + lq;
                bf16x8 af = wAv[(size_t)kb * 256 + o];
#pragma unroll
                for (int nf = 0; nf < 2; ++nf)
                    acc[mf][nf] = __builtin_amdgcn_mfma_f32_16x16x32_bf16(
                        af, bfr[nf], acc[mf][nf], 0, 0, 0);
            }
        }

        // ---- write next tile (loads have landed under MFMA) ----
        if (ch < 7) {
            unsigned int* tWw = reinterpret_cast<unsigned int*>(sR);
#pragma unroll
            for (int i = 0; i < 7; ++i)
                if (stg[i] >= 0)
                    tWw[stg[i] & 0xFFF] =
                        f2bf(L0[i]) | ((unsigned int)f2bf(L1[i]) << 16);
        }
        __syncthreads();        // sS free + next tile ready
    }

    // ---- epilogue: D row = lq*4 + r, col = lm ----
#pragma unroll
    for (int mf = 0; mf < 2; ++mf) {
#pragma unroll
        for (int r = 0; r < 4; ++r) {
            int o = wv * 32 + mf * 16 + lq * 4 + r;
            float bo = b_dc[o];
#pragma unroll
            for (int nf = 0; nf < 2; ++nf) {
                int p = nf * 16 + lm;
                out[((size_t)(b * 256 + o)) * HW + h * WW + w0 + p] = acc[mf][nf][r] + bo;
            }
        }
    }
}

extern "C" void kernel_launch(void* const* d_in, const int* in_sizes, int n_in,
                              void* d_out, int out_size, void* d_ws, size_t ws_size,
                              hipStream_t stream) {
    const float* x    = (const float*)d_in[0];
    const float* w_om = (const float*)d_in[1];
    const float* b_om = (const float*)d_in[2];
    const float* w_dc = (const float*)d_in[3];
    const float* b_dc = (const float*)d_in[4];
    float* out = (float*)d_out;

    unsigned short* wA   = (unsigned short*)d_ws;                    // 1,179,648 B
    unsigned short* wOmA = (unsigned short*)((char*)d_ws + 1179648); //   147,456 B

    wprep_kernel<<<(256 * KTOT) / 256, 256, 0, stream>>>(w_dc, wA);
    womprep_kernel<<<73728 / 256, 256, 0, stream>>>(w_om, wOmA);
    deform_mfma_kernel<<<BB * HH * 2, 512, 0, stream>>>(x, wOmA, b_om, wA, b_dc, out);
}